// Round 6
// baseline (106.989 us; speedup 1.0000x reference)
//
#include <hip/hip_runtime.h>
#include <hip/hip_bf16.h>

typedef unsigned short u16;
typedef __attribute__((ext_vector_type(8))) short short8;
typedef __attribute__((ext_vector_type(4))) float f32x4;

#define B_ 32
#define L_ 1024
#define D_ 1024
#define E_ 100
#define E1_ 101
#define M2_ (B_ * E1_)     // 3232 entity rows (incl. none-entity)
#define M2P_ 3328          // padded to 26*128 for the 128-row MFMA tiles
#define QBLK_ 32
#define NBLK3_ 7           // tiles that can contain valid rows (Q_MAX=200 < 7*32)
#define NTILES_ (L_ / QBLK_)   // 32 tiles per batch

#define MFMA16(a, b, c) __builtin_amdgcn_mfma_f32_16x16x32_bf16((a), (b), (c), 0, 0, 0)

__device__ __forceinline__ void split2(float x, u16& h, u16& l) {
    __hip_bfloat16 bh = __float2bfloat16(x);          // RN
    float r = x - __bfloat162float(bh);
    __hip_bfloat16 bl = __float2bfloat16(r);
    h = __builtin_bit_cast(u16, bh);
    l = __builtin_bit_cast(u16, bl);
}

// async global->LDS, 16B per lane; LDS dest = wave-uniform base + lane*16
__device__ __forceinline__ void gload16(const void* g, void* l) {
    __builtin_amdgcn_global_load_lds(
        (const __attribute__((address_space(1))) unsigned int*)g,
        (__attribute__((address_space(3))) unsigned int*)l, 16, 0, 0);
}

// ---------------- K1: fused [encode (blocks 0..M2_-1)] | [wsplit (blocks M2_..M2_+1023)]
__global__ __launch_bounds__(256) void k_prep(const float* __restrict__ q_enc,
                                              const float* __restrict__ none_ent,
                                              const float* __restrict__ W,
                                              const float* __restrict__ bias,
                                              const int* __restrict__ ranges,
                                              u16* __restrict__ enc_hi, u16* __restrict__ enc_lo,
                                              u16* __restrict__ w_hi, u16* __restrict__ w_lo,
                                              float* __restrict__ ep_last) {
    __shared__ float red4[4];
    int id = blockIdx.x;
    int t = threadIdx.x, c = t * 4;
    if (id >= M2_) {
        // ---- wsplit unit: one W row
        int r = id - M2_;
        float4 v = *(const float4*)&W[(size_t)r * 1024 + c];
        union { u16 u[4]; float2 f; } ph, pl;
        split2(v.x, ph.u[0], pl.u[0]); split2(v.y, ph.u[1], pl.u[1]);
        split2(v.z, ph.u[2], pl.u[2]); split2(v.w, ph.u[3], pl.u[3]);
        *(float2*)&w_hi[(size_t)r * 1024 + c] = ph.f;
        *(float2*)&w_lo[(size_t)r * 1024 + c] = pl.f;
        return;
    }
    // ---- encode unit: one (b, e) entity row
    int b = id / E1_, e = id - b * E1_;
    float4 acc;
    if (e == E_) {
        acc = *(const float4*)&none_ent[c];
    } else {
        acc = make_float4(0.f, 0.f, 0.f, 0.f);
        int r0 = ranges[(b * E_ + e) * 2 + 0];
        int r1 = ranges[(b * E_ + e) * 2 + 1];
        for (int l = r0 + 1; l < r1; ++l) {
            float4 v = *(const float4*)&q_enc[((size_t)b * L_ + l) * D_ + c];
            acc.x += v.x; acc.y += v.y; acc.z += v.z; acc.w += v.w;
        }
    }
    union { u16 u[4]; float2 f; } ph, pl;
    split2(acc.x, ph.u[0], pl.u[0]); split2(acc.y, ph.u[1], pl.u[1]);
    split2(acc.z, ph.u[2], pl.u[2]); split2(acc.w, ph.u[3], pl.u[3]);
    *(float2*)&enc_hi[(size_t)id * 1024 + c] = ph.f;
    *(float2*)&enc_lo[(size_t)id * 1024 + c] = pl.f;
    // fused last column (hint-weight row of W)
    const float* w1k = W + (size_t)1024 * 1024;
    float4 wv = *(const float4*)&w1k[c];
    float s = acc.x * wv.x + acc.y * wv.y + acc.z * wv.z + acc.w * wv.w;
    #pragma unroll
    for (int off = 32; off; off >>= 1) s += __shfl_down(s, off);
    if ((t & 63) == 0) red4[t >> 6] = s;
    __syncthreads();
    if (t == 0) ep_last[id] = red4[0] + red4[1] + red4[2] + red4[3] + bias[1024];
}

// ---------------- K2: ep = enc . W^T + bias, 3-term bf16 MFMA (128x128 tile, gload_lds)
__global__ __launch_bounds__(256, 2) void k_entproj(const u16* __restrict__ A_hi, const u16* __restrict__ A_lo,
                                                    const u16* __restrict__ B_hi, const u16* __restrict__ B_lo,
                                                    const float* __restrict__ bias,
                                                    u16* __restrict__ ep_hi, u16* __restrict__ ep_lo,
                                                    int* __restrict__ cnt) {
    __shared__ __attribute__((aligned(16))) u16 Ah[128 * 64], Al[128 * 64], Bh[128 * 64], Bl[128 * 64];
    int tid = threadIdx.x;
    if (blockIdx.x == 0 && blockIdx.y == 0 && tid < B_) cnt[tid] = 0;  // reset tile counters for K3
    int m0 = blockIdx.y * 128, n0 = blockIdx.x * 128;
    int w = tid >> 6, lane = tid & 63, lr = lane & 15, lg = lane >> 4;
    int wr = w >> 1, wc = w & 1;
    f32x4 zero = {0.f, 0.f, 0.f, 0.f};
    f32x4 acc[4][4];
    #pragma unroll
    for (int i = 0; i < 4; ++i)
        #pragma unroll
        for (int j = 0; j < 4; ++j) acc[i][j] = zero;
    int sb = w * 256;                 // wave's slot base (of 1024 slots/array)
    for (int k0 = 0; k0 < 1024; k0 += 64) {
        #pragma unroll
        for (int j = 0; j < 4; ++j) {
            int slot = sb + j * 64 + lane;      // slot = r*8 + s
            int r = slot >> 3, s = slot & 7;
            int g = (s ^ (r & 7)) << 3;         // pre-swizzled source column group
            size_t ga = (size_t)(m0 + r) * 1024 + k0 + g;
            size_t gb = (size_t)(n0 + r) * 1024 + k0 + g;
            int ld = (sb + j * 64) * 8;         // wave-uniform LDS base (u16 idx)
            gload16(&A_hi[ga], &Ah[ld]);
            gload16(&A_lo[ga], &Al[ld]);
            gload16(&B_hi[gb], &Bh[ld]);
            gload16(&B_lo[gb], &Bl[ld]);
        }
        __syncthreads();
        #pragma unroll
        for (int half = 0; half < 2; ++half) {
            int sk = half * 4 + lg;
            short8 a_h[4], a_l[4], b_h[4], b_l[4];
            #pragma unroll
            for (int mf = 0; mf < 4; ++mf) {
                int R = wr * 64 + mf * 16 + lr;
                int ad = R * 64 + ((sk ^ (R & 7)) << 3);
                a_h[mf] = __builtin_bit_cast(short8, *(const float4*)&Ah[ad]);
                a_l[mf] = __builtin_bit_cast(short8, *(const float4*)&Al[ad]);
            }
            #pragma unroll
            for (int nf = 0; nf < 4; ++nf) {
                int R = wc * 64 + nf * 16 + lr;
                int ad = R * 64 + ((sk ^ (R & 7)) << 3);
                b_h[nf] = __builtin_bit_cast(short8, *(const float4*)&Bh[ad]);
                b_l[nf] = __builtin_bit_cast(short8, *(const float4*)&Bl[ad]);
            }
            #pragma unroll
            for (int mf = 0; mf < 4; ++mf)
                #pragma unroll
                for (int nf = 0; nf < 4; ++nf) {
                    acc[mf][nf] = MFMA16(a_h[mf], b_h[nf], acc[mf][nf]);
                    acc[mf][nf] = MFMA16(a_h[mf], b_l[nf], acc[mf][nf]);
                    acc[mf][nf] = MFMA16(a_l[mf], b_h[nf], acc[mf][nf]);
                }
        }
        __syncthreads();
    }
    #pragma unroll
    for (int mf = 0; mf < 4; ++mf)
        #pragma unroll
        for (int nf = 0; nf < 4; ++nf)
            #pragma unroll
            for (int reg = 0; reg < 4; ++reg) {
                int m = m0 + wr * 64 + mf * 16 + lg * 4 + reg;
                if (m < M2_) {
                    int n = n0 + wc * 64 + nf * 16 + lr;
                    float v = acc[mf][nf][reg] + bias[n];
                    u16 h, l;
                    split2(v, h, l);
                    ep_hi[(size_t)m * 1024 + n] = h;
                    ep_lo[(size_t)m * 1024 + n] = l;
                }
            }
}

// ---------------- K3: flat grid 1024 = [heavy score tiles: id<224] | [zero-fill tiles]
// heavy: scores MFMA + softmax + co_att + partial; last tile per batch reduces att.
__global__ __launch_bounds__(256) void k_scores_all(const float* __restrict__ q_enc,
                                                    const float* __restrict__ hint,
                                                    const u16* __restrict__ ep_hi, const u16* __restrict__ ep_lo,
                                                    const float* __restrict__ ep_last,
                                                    const int* __restrict__ qlen,
                                                    float* __restrict__ co_att,
                                                    float* __restrict__ partial,
                                                    int* __restrict__ cnt,
                                                    float* __restrict__ att) {
    __shared__ __attribute__((aligned(16))) u16 Ah[32 * 64], Al[32 * 64], Bh[128 * 64], Bl[128 * 64];
    __shared__ float Ss[32 * 113];
    __shared__ float red[QBLK_][8];
    __shared__ int winner;
    int id = blockIdx.x;
    int b = id & 31, mt = id >> 5, l0 = mt * QBLK_;
    int tid = threadIdx.x;
    if (mt >= NBLK3_) {
        // ---- light unit: zero co_att tile (these rows are always masked)
        float* base = &co_att[((size_t)b * L_ + l0) * E1_];
        float4 z = make_float4(0.f, 0.f, 0.f, 0.f);
        for (int i = tid; i < QBLK_ * E1_ / 4; i += 256)
            *(float4*)&base[i * 4] = z;
        return;
    }
    int qn = qlen[b];
    if (l0 >= qn) {
        // masked heavy tile: zero co_att rows + zero partial, then join the counter
        float* base = &co_att[((size_t)b * L_ + l0) * E1_];
        float4 z = make_float4(0.f, 0.f, 0.f, 0.f);
        for (int i = tid; i < QBLK_ * E1_ / 4; i += 256)
            *(float4*)&base[i * 4] = z;
        for (int e = tid; e < E1_; e += 256)
            partial[((size_t)b * NBLK3_ + mt) * E1_ + e] = 0.f;
    } else {
        int w = tid >> 6, lane = tid & 63, lr = lane & 15, lg = lane >> 4;
        int mf = w & 1, nb = (w >> 1) * 4, nc = (w >> 1) ? 3 : 4;
        int sb = w * 256;
        f32x4 zero = {0.f, 0.f, 0.f, 0.f};
        f32x4 acc[4] = {zero, zero, zero, zero};
        for (int k0 = 0; k0 < 1024; k0 += 64) {
            {   // B: 128 rows x 64 k via gload_lds (rows >100 are finite garbage, masked later)
                #pragma unroll
                for (int j = 0; j < 4; ++j) {
                    int slot = sb + j * 64 + lane;
                    int r = slot >> 3, s = slot & 7;
                    int g = (s ^ (r & 7)) << 3;
                    size_t gb = ((size_t)b * E1_ + r) * 1024 + k0 + g;
                    int ld = (sb + j * 64) * 8;
                    gload16(&ep_hi[gb], &Bh[ld]);
                    gload16(&ep_lo[gb], &Bl[ld]);
                }
            }
            {   // A: 32 rows x 64 k, split fp32 -> hi/lo on the fly (1 slot per thread)
                int r = tid >> 3, s = tid & 7;
                const float* src = &q_enc[((size_t)b * L_ + l0 + r) * D_ + k0 + s * 8];
                float4 x0 = *(const float4*)src, x1 = *(const float4*)(src + 4);
                float xs[8] = {x0.x, x0.y, x0.z, x0.w, x1.x, x1.y, x1.z, x1.w};
                short8 hv, lv;
                #pragma unroll
                for (int j = 0; j < 8; ++j) {
                    u16 hh, ll;
                    split2(xs[j], hh, ll);
                    hv[j] = (short)hh; lv[j] = (short)ll;
                }
                int dst = r * 64 + ((s ^ (r & 7)) << 3);
                *(float4*)&Ah[dst] = __builtin_bit_cast(float4, hv);
                *(float4*)&Al[dst] = __builtin_bit_cast(float4, lv);
            }
            __syncthreads();
            #pragma unroll
            for (int ks = 0; ks < 64; ks += 32) {
                int sk = (ks >> 3) + lg;
                int rA = mf * 16 + lr;
                int adA = rA * 64 + ((sk ^ (rA & 7)) << 3);
                short8 ah = __builtin_bit_cast(short8, *(const float4*)&Ah[adA]);
                short8 al = __builtin_bit_cast(short8, *(const float4*)&Al[adA]);
                #pragma unroll
                for (int nf = 0; nf < 4; ++nf) {
                    if (nf < nc) {
                        int rB = (nb + nf) * 16 + lr;
                        int adB = rB * 64 + ((sk ^ (rB & 7)) << 3);
                        short8 bh = __builtin_bit_cast(short8, *(const float4*)&Bh[adB]);
                        short8 bl = __builtin_bit_cast(short8, *(const float4*)&Bl[adB]);
                        acc[nf] = MFMA16(ah, bh, acc[nf]);
                        acc[nf] = MFMA16(ah, bl, acc[nf]);
                        acc[nf] = MFMA16(al, bh, acc[nf]);
                    }
                }
            }
            __syncthreads();
        }
        #pragma unroll
        for (int nf = 0; nf < 4; ++nf)
            if (nf < nc) {
                #pragma unroll
                for (int reg = 0; reg < 4; ++reg)
                    Ss[(mf * 16 + lg * 4 + reg) * 113 + (nb + nf) * 16 + lr] = acc[nf][reg];
            }
        __syncthreads();
        // ---- softmax over 101 entities per row
        int l = tid & 31, eg = tid >> 5;
        float h = hint[(size_t)b * L_ + l0 + l];
        float sc[13];
        #pragma unroll
        for (int j = 0; j < 13; ++j) {
            int e = eg + 8 * j;
            sc[j] = (e < E1_) ? (Ss[l * 113 + e] + h * ep_last[b * E1_ + e]) : -3.4e38f;
        }
        float mloc = -3.4e38f;
        #pragma unroll
        for (int j = 0; j < 13; ++j) mloc = fmaxf(mloc, sc[j]);
        red[l][eg] = mloc;
        __syncthreads();
        float m = red[l][0];
        #pragma unroll
        for (int k = 1; k < 8; ++k) m = fmaxf(m, red[l][k]);
        __syncthreads();
        float p[13];
        float sloc = 0.f;
        #pragma unroll
        for (int j = 0; j < 13; ++j) {
            p[j] = 0.f;
            if (eg + 8 * j < E1_) { p[j] = __expf(sc[j] - m); sloc += p[j]; }
        }
        red[l][eg] = sloc;
        __syncthreads();
        float ssum = 0.f;
        #pragma unroll
        for (int k = 0; k < 8; ++k) ssum += red[l][k];
        float inv = 1.f / ssum;
        bool valid = (l0 + l) < qn;
        float maskv = valid ? inv : 0.f;
        float* row = &co_att[((size_t)b * L_ + l0 + l) * E1_];
        #pragma unroll
        for (int j = 0; j < 13; ++j) {
            int e = eg + 8 * j;
            if (e < E1_) row[e] = p[j] * maskv;
        }
        #pragma unroll
        for (int j = 0; j < 13; ++j) {
            int e = eg + 8 * j;
            float v = (e < E1_) ? p[j] * maskv : 0.f;
            v += __shfl_xor(v, 1);  v += __shfl_xor(v, 2);
            v += __shfl_xor(v, 4);  v += __shfl_xor(v, 8);
            v += __shfl_xor(v, 16);
            if ((tid & 31) == 0 && e < E1_)
                partial[((size_t)b * NBLK3_ + mt) * E1_ + e] = v;
        }
    }
    // ---- last tile of this batch reduces att[b,:] (deterministic fixed-order sum)
    __threadfence();
    if (tid == 0) {
        int old = atomicAdd(&cnt[b], 1);
        winner = (old == NBLK3_ - 1);
    }
    __syncthreads();
    if (winner) {
        __threadfence();
        for (int e = tid; e < E_; e += 256) {
            float s = 0.f;
            #pragma unroll
            for (int k = 0; k < NBLK3_; ++k) s += partial[((size_t)b * NBLK3_ + k) * E1_ + e];
            att[b * E_ + e] = fminf(s, 1.f);
        }
    }
}

extern "C" void kernel_launch(void* const* d_in, const int* in_sizes, int n_in,
                              void* d_out, int out_size, void* d_ws, size_t ws_size,
                              hipStream_t stream) {
    const float* q_enc    = (const float*)d_in[0];
    const float* hint     = (const float*)d_in[1];
    const float* W        = (const float*)d_in[2];
    const float* bias     = (const float*)d_in[3];
    const float* none_ent = (const float*)d_in[4];
    const int*   qlen     = (const int*)d_in[5];
    const int*   ranges   = (const int*)d_in[6];

    float* att    = (float*)d_out;
    float* co_att = att + (size_t)B_ * E_;

    u16* enc_hi = (u16*)d_ws;
    u16* enc_lo = enc_hi + (size_t)M2P_ * 1024;
    u16* w_hi   = enc_lo + (size_t)M2P_ * 1024;
    u16* w_lo   = w_hi + (size_t)1024 * 1024;
    u16* ep_hi  = w_lo + (size_t)1024 * 1024;
    u16* ep_lo  = ep_hi + (size_t)M2P_ * 1024;
    float* ep_last = (float*)(ep_lo + (size_t)M2P_ * 1024);
    float* part    = ep_last + M2P_;
    int*   cnt     = (int*)(part + (size_t)B_ * NBLK3_ * E1_);

    k_prep<<<M2_ + 1024, 256, 0, stream>>>(q_enc, none_ent, W, bias, ranges,
                                           enc_hi, enc_lo, w_hi, w_lo, ep_last);
    k_entproj<<<dim3(8, 26), 256, 0, stream>>>(enc_hi, enc_lo, w_hi, w_lo, bias, ep_hi, ep_lo, cnt);
    k_scores_all<<<B_ * NTILES_, 256, 0, stream>>>(q_enc, hint, ep_hi, ep_lo, ep_last, qlen,
                                                   co_att, part, cnt, att);
}